// Round 1
// baseline (195.260 us; speedup 1.0000x reference)
//
#include <hip/hip_runtime.h>

#define IN_H 512
#define IN_W 512

// Block: 256 threads, one 8-row x 256-col strip (32 tiles x 3 channels).
// Grid: 32 batches * 64 strip-rows * 2 strip-cols = 4096 blocks.
//
// LDS map (bytes):                                 alias (later phase)
//  Ys   @     0 : 8 x 258 doubles = 16512          V0: 8 x 260 f32 (8320)
//  CbS  @ 16512 : 4 x 130 doubles (4160/8320 rgn)  V1: 8 x 260 f32 (8320)
//  CrS  @ 24832 : 4 x 130 doubles (4160/8320 rgn)  V2: 8 x 260 f32 (8320)
//  T    @ 33152 : 32 tiles x 68 doubles = 17408    U: 32 x 68 f32 (8704)
//  Z    @ 50560 : 32 tiles x 68 f32 = 8704
//  qtab @ 59264 : 192 x {double inv, double q} = 3072
//  Df   @ 62336 : 64 f32 = 256
//  total 62592  -> 2 blocks/CU (LDS-bound), so VGPRs up to 256 are free.

__global__ __launch_bounds__(256, 2) void jpeg_kernel(
    const float* __restrict__ in, const float* __restrict__ qz,
    const float* __restrict__ dmtx, float* __restrict__ out)
{
    __shared__ __align__(16) unsigned char smem[62592];
    double* Ys   = (double*)(smem);
    double* CbS  = (double*)(smem + 16512);
    double* CrS  = (double*)(smem + 24832);
    double* T    = (double*)(smem + 33152);
    float*  U    = (float*) (smem + 33152);
    float*  Z    = (float*) (smem + 50560);
    double* qtab = (double*)(smem + 59264);
    float*  Df   = (float*) (smem + 62336);
    float* V[3]  = { (float*)(smem), (float*)(smem + 16512), (float*)(smem + 24832) };

    const int t   = threadIdx.x;
    const int blk = blockIdx.x;
    const int b   = blk >> 7;
    const int rr  = blk & 127;
    const int row0 = (rr >> 1) << 3;
    const int col0 = (rr & 1) << 8;
    const int chs = IN_H * IN_W;

    // ---- P0: quant + DCT tables into LDS ----
    if (t < 192) {
        double v  = (double)qz[t];
        double t0 = rint(v * 255.0);
        double t1 = rint((t0 * 50.0 + 50.0) / 100.0);   // true division: exact .5 ties!
        double q  = fmin(fmax(t1, 1.0), 255.0);
        qtab[2*t]   = 1.0 / q;
        qtab[2*t+1] = q;
    }
    if (t < 64) Df[t] = dmtx[t];

    // ---- P1: load, RGB->YCbCr (f64), subsample, stage to LDS ----
    const int s  = t >> 6;   // row-pair 0..3
    const int c4 = t & 63;   // 4-col group
    {
        const int base = ((b*3) * IN_H + row0 + 2*s) * IN_W + col0 + 4*c4;
        float4 ra = *(const float4*)(in + base);
        float4 rb = *(const float4*)(in + base + IN_W);
        float4 ga = *(const float4*)(in + base + chs);
        float4 gb = *(const float4*)(in + base + chs + IN_W);
        float4 ba = *(const float4*)(in + base + 2*chs);
        float4 bb = *(const float4*)(in + base + 2*chs + IN_W);

        float rA[2][4] = {{ra.x,ra.y,ra.z,ra.w},{rb.x,rb.y,rb.z,rb.w}};
        float gA[2][4] = {{ga.x,ga.y,ga.z,ga.w},{gb.x,gb.y,gb.z,gb.w}};
        float bA[2][4] = {{ba.x,ba.y,ba.z,ba.w},{bb.x,bb.y,bb.z,bb.w}};

        double yv[2][4], cbv[2][4], crv[2][4];
        #pragma unroll
        for (int p = 0; p < 2; ++p) {
            #pragma unroll
            for (int k = 0; k < 4; ++k) {
                double R = 255.0 * (double)rA[p][k];
                double G = 255.0 * (double)gA[p][k];
                double B = 255.0 * (double)bA[p][k];
                double y  =  0.299*R + 0.587*G + 0.114*B;
                double cb = -0.168735892*R - 0.331264108*G + 0.5*B + 128.0;
                double cr =  0.5*R - 0.418687589*G - 0.081312411*B + 128.0;
                yv[p][k]  = fmin(fmax(y , 0.0), 255.0) - 128.0;
                cbv[p][k] = fmin(fmax(cb, 0.0), 255.0);
                crv[p][k] = fmin(fmax(cr, 0.0), 255.0);
            }
        }
        #pragma unroll
        for (int p = 0; p < 2; ++p) {
            double* yp = &Ys[(2*s+p)*258 + 4*c4];
            *(double2*)(yp)     = make_double2(yv[p][0], yv[p][1]);
            *(double2*)(yp + 2) = make_double2(yv[p][2], yv[p][3]);
        }
        double m0 = (cbv[0][0]+cbv[0][1]+cbv[1][0]+cbv[1][1])*0.25 - 128.0;
        double m1 = (cbv[0][2]+cbv[0][3]+cbv[1][2]+cbv[1][3])*0.25 - 128.0;
        *(double2*)&CbS[s*130 + 2*c4] = make_double2(m0, m1);
        double n0 = (crv[0][0]+crv[0][1]+crv[1][0]+crv[1][1])*0.25 - 128.0;
        double n1 = (crv[0][2]+crv[0][3]+crv[1][2]+crv[1][3])*0.25 - 128.0;
        *(double2*)&CrS[s*130 + 2*c4] = make_double2(n0, n1);
    }
    __syncthreads();

    // ---- P2: per-channel DCT -> quant -> IDCT through LDS ----
    // D half-tables in registers (even/odd symmetry: D[l][7-k] = (-1)^l D[l][k])
    float  dh[8][4];
    double dh64[8][4];
    #pragma unroll
    for (int l = 0; l < 8; ++l) {
        float4 d4 = *(const float4*)&Df[l*8];
        dh[l][0]=d4.x; dh[l][1]=d4.y; dh[l][2]=d4.z; dh[l][3]=d4.w;
        #pragma unroll
        for (int k = 0; k < 4; ++k) dh64[l][k] = (double)dh[l][k];
    }
    const int q8 = t >> 3;   // tile 0..31
    const int jl = t & 7;    // row (F1/I1) or col (F2/I2)

    #pragma unroll
    for (int c = 0; c < 3; ++c) {
        // F1: row DCT (f64): T[j][l] = sum_k X[j][k] D[l][k]
        {
            double x[8];
            if (c == 0) {
                const double* p = &Ys[jl*258 + q8*8];
                double2 a0 = *(const double2*)(p);
                double2 a1 = *(const double2*)(p+2);
                double2 a2 = *(const double2*)(p+4);
                double2 a3 = *(const double2*)(p+6);
                x[0]=a0.x; x[1]=a0.y; x[2]=a1.x; x[3]=a1.y;
                x[4]=a2.x; x[5]=a2.y; x[6]=a3.x; x[7]=a3.y;
            } else {
                const double* p = (c==1 ? CbS : CrS) + (jl>>1)*130 + q8*4;
                double2 a0 = *(const double2*)(p);
                double2 a1 = *(const double2*)(p+2);
                x[0]=a0.x; x[1]=a0.x; x[2]=a0.y; x[3]=a0.y;
                x[4]=a1.x; x[5]=a1.x; x[6]=a1.y; x[7]=a1.y;
            }
            double e[4], o[4];
            #pragma unroll
            for (int k = 0; k < 4; ++k) { e[k]=x[k]+x[7-k]; o[k]=x[k]-x[7-k]; }
            double* Tp = &T[q8*68 + jl*8];
            #pragma unroll
            for (int l = 0; l < 8; l += 2) {
                double te = dh64[l  ][0]*e[0] + dh64[l  ][1]*e[1] + dh64[l  ][2]*e[2] + dh64[l  ][3]*e[3];
                double to = dh64[l+1][0]*o[0] + dh64[l+1][1]*o[1] + dh64[l+1][2]*o[2] + dh64[l+1][3]*o[3];
                *(double2*)(Tp + l) = make_double2(te, to);
            }
        }
        __syncthreads();

        // F2: col DCT (f64) + quantize/dequantize -> Z (f32, exact integers)
        {
            const double* Tc = &T[q8*68 + jl];
            double tc[8];
            #pragma unroll
            for (int j2 = 0; j2 < 8; ++j2) tc[j2] = Tc[j2*8];
            double e2[4], o2[4];
            #pragma unroll
            for (int m = 0; m < 4; ++m) { e2[m]=tc[m]+tc[7-m]; o2[m]=tc[m]-tc[7-m]; }
            float* Zc = &Z[q8*68 + jl];
            #pragma unroll
            for (int i = 0; i < 8; ++i) {
                double acc;
                if ((i & 1) == 0)
                    acc = dh64[i][0]*e2[0]+dh64[i][1]*e2[1]+dh64[i][2]*e2[2]+dh64[i][3]*e2[3];
                else
                    acc = dh64[i][0]*o2[0]+dh64[i][1]*o2[1]+dh64[i][2]*o2[2]+dh64[i][3]*o2[3];
                double2 qe = *(const double2*)&qtab[2*(c*64 + i*8 + jl)];
                double comp = rint(acc * qe.x);
                Zc[i*8] = (float)(comp * qe.y);
            }
        }
        __syncthreads();

        // I1: row IDCT (f32): U[j][l] = sum_k Z[j][k] D[k][l]
        {
            const float* Zp = &Z[q8*68 + jl*8];
            float4 z0 = *(const float4*)(Zp);
            float4 z1 = *(const float4*)(Zp+4);
            float zz[8] = {z0.x,z0.y,z0.z,z0.w,z1.x,z1.y,z1.z,z1.w};
            float se[4], so[4], uu[8];
            #pragma unroll
            for (int l2 = 0; l2 < 4; ++l2) {
                se[l2] = zz[0]*dh[0][l2] + zz[2]*dh[2][l2] + zz[4]*dh[4][l2] + zz[6]*dh[6][l2];
                so[l2] = zz[1]*dh[1][l2] + zz[3]*dh[3][l2] + zz[5]*dh[5][l2] + zz[7]*dh[7][l2];
            }
            #pragma unroll
            for (int l2 = 0; l2 < 4; ++l2) { uu[l2]=se[l2]+so[l2]; uu[7-l2]=se[l2]-so[l2]; }
            float* Upp = &U[q8*68 + jl*8];
            *(float4*)(Upp)   = make_float4(uu[0],uu[1],uu[2],uu[3]);
            *(float4*)(Upp+4) = make_float4(uu[4],uu[5],uu[6],uu[7]);
        }
        __syncthreads();

        // I2: col IDCT (f32) -> V[c] plane (pixel layout)
        {
            const float* Up2 = &U[q8*68 + jl];
            float uu[8];
            #pragma unroll
            for (int j2 = 0; j2 < 8; ++j2) uu[j2] = Up2[j2*8];
            float se[4], so[4];
            #pragma unroll
            for (int i2 = 0; i2 < 4; ++i2) {
                se[i2] = uu[0]*dh[0][i2] + uu[2]*dh[2][i2] + uu[4]*dh[4][i2] + uu[6]*dh[6][i2];
                so[i2] = uu[1]*dh[1][i2] + uu[3]*dh[3][i2] + uu[5]*dh[5][i2] + uu[7]*dh[7][i2];
            }
            float* Vc = V[c];
            #pragma unroll
            for (int i2 = 0; i2 < 4; ++i2) {
                Vc[i2*260     + q8*8 + jl] = se[i2] + so[i2];
                Vc[(7-i2)*260 + q8*8 + jl] = se[i2] - so[i2];
            }
        }
        __syncthreads();
    }

    // ---- P3: YCbCr->RGB (f32), round, store ----
    {
        const int obase = ((b*3) * IN_H + row0 + 2*s) * IN_W + col0 + 4*c4;
        #pragma unroll
        for (int p = 0; p < 2; ++p) {
            const int roff = (2*s+p)*260 + 4*c4;
            float4 vy = *(const float4*)&V[0][roff];
            float4 vb = *(const float4*)&V[1][roff];
            float4 vr = *(const float4*)&V[2][roff];
            float yv2[4]={vy.x,vy.y,vy.z,vy.w};
            float cb2[4]={vb.x,vb.y,vb.z,vb.w};
            float cr2[4]={vr.x,vr.y,vr.z,vr.w};
            float R4[4],G4[4],B4[4];
            #pragma unroll
            for (int k = 0; k < 4; ++k) {
                float im0 = yv2[k] + 128.0f;
                float im1 = cb2[k];
                float im2 = cr2[k];
                float R = fminf(fmaxf(im0 + 1.402f*im2, 0.0f), 255.0f);
                float G = fminf(fmaxf(im0 - 0.344136286f*im1 - 0.714136286f*im2, 0.0f), 255.0f);
                float B = fminf(fmaxf(im0 + 1.772f*im1, 0.0f), 255.0f);
                R4[k] = rintf(R) * (1.0f/255.0f);
                G4[k] = rintf(G) * (1.0f/255.0f);
                B4[k] = rintf(B) * (1.0f/255.0f);
            }
            float* op = out + obase + p*IN_W;
            *(float4*)(op)         = make_float4(R4[0],R4[1],R4[2],R4[3]);
            *(float4*)(op + chs)   = make_float4(G4[0],G4[1],G4[2],G4[3]);
            *(float4*)(op + 2*chs) = make_float4(B4[0],B4[1],B4[2],B4[3]);
        }
    }
}

extern "C" void kernel_launch(void* const* d_in, const int* in_sizes, int n_in,
                              void* d_out, int out_size, void* d_ws, size_t ws_size,
                              hipStream_t stream) {
    (void)in_sizes; (void)n_in; (void)out_size; (void)d_ws; (void)ws_size;
    const float* in  = (const float*)d_in[0];
    const float* qz  = (const float*)d_in[1];
    const float* dm  = (const float*)d_in[2];
    float* out = (float*)d_out;
    dim3 grid(4096), blk(256);
    hipLaunchKernelGGL(jpeg_kernel, grid, blk, 0, stream, in, qz, dm, out);
}